// Round 4
// baseline (44.441 us; speedup 1.0000x reference)
//
#include <hip/hip_runtime.h>
#include <hip/hip_cooperative_groups.h>

namespace cg = cooperative_groups;

// DigitCapsules: routing collapses analytically (u_hat constant over capsule
// axis -> softmax stays uniform every iteration -> v[b,i,:] =
// squash(mean_r u_core[b,r,:]), identical for all 576 capsules i).
//
// x: [32, 8, 24, 24] fp32, W: [32, 576, 8, 16] fp32, out: [32, 576, 16] fp32.
//
// Single cooperative kernel, 288 blocks x 64 threads (full-width both phases):
//   phase 1 (== R3 kernel A): block (b,blk) -> wave partial of sum_r u_core
//   grid.sync()
//   phase 2 (== R3 kernel B): same block folds 9 partials, squash, writes
//     256 float4 of out[b] (1 full capsule vector per thread).

#define NB 32
#define NR 576
#define NC 8
#define ND 16
#define NW 9

__global__ __launch_bounds__(64) void caps_coop(const float* __restrict__ x,
                                                const float* __restrict__ W,
                                                float* __restrict__ out,
                                                float* __restrict__ partial) {
    const int g    = blockIdx.x;          // 0..287
    const int lane = threadIdx.x;         // 0..63
    const int b    = g / NW;
    const int blk  = g - b * NW;          // 0..8
    const int r    = blk * 64 + lane;     // 9*64 = 576

    // ---------- phase 1: partial of sum_r u_core[b,r,:] ----------
    const float* xb = x + (size_t)b * NC * NR;
    const float* Wr = W + ((size_t)b * NR + r) * NC * ND;

    float xv[NC];
#pragma unroll
    for (int k = 0; k < NC; ++k) xv[k] = xb[k * NR + r];   // x2[b,r,k]=x[b,k,r]

    float acc[ND];
#pragma unroll
    for (int j = 0; j < ND; ++j) acc[j] = 0.f;

#pragma unroll
    for (int k = 0; k < NC; ++k) {        // 512 B/lane contiguous W reads
        const float4 w0 = *reinterpret_cast<const float4*>(Wr + k * ND + 0);
        const float4 w1 = *reinterpret_cast<const float4*>(Wr + k * ND + 4);
        const float4 w2 = *reinterpret_cast<const float4*>(Wr + k * ND + 8);
        const float4 w3 = *reinterpret_cast<const float4*>(Wr + k * ND + 12);
        const float xk = xv[k];
        acc[0]  += xk * w0.x;  acc[1]  += xk * w0.y;
        acc[2]  += xk * w0.z;  acc[3]  += xk * w0.w;
        acc[4]  += xk * w1.x;  acc[5]  += xk * w1.y;
        acc[6]  += xk * w1.z;  acc[7]  += xk * w1.w;
        acc[8]  += xk * w2.x;  acc[9]  += xk * w2.y;
        acc[10] += xk * w2.z;  acc[11] += xk * w2.w;
        acc[12] += xk * w3.x;  acc[13] += xk * w3.y;
        acc[14] += xk * w3.z;  acc[15] += xk * w3.w;
    }

#pragma unroll
    for (int j = 0; j < ND; ++j) {        // 64-lane butterfly reduce
#pragma unroll
        for (int m = 1; m < 64; m <<= 1)
            acc[j] += __shfl_xor(acc[j], m, 64);
    }

    if (lane == 0) {
        float* p = partial + ((size_t)b * NW + blk) * ND;
#pragma unroll
        for (int j = 0; j < ND; ++j) p[j] = acc[j];
    }

    // ---------- grid-wide barrier (device-scope acq/rel fences inside) ----
    cg::this_grid().sync();

    // ---------- phase 2: fold partials, squash, broadcast-write ----------
    __shared__ float sv[ND];
    if (lane < ND) {
        const float* p = partial + (size_t)b * NW * ND + lane;
        float sj = 0.f;
#pragma unroll
        for (int q = 0; q < NW; ++q) sj += p[q * ND];
        sv[lane] = sj * (1.0f / 576.0f);  // uniform softmax coefficient
    }
    __syncthreads();

    float norm = 0.f;
#pragma unroll
    for (int j = 0; j < ND; ++j) norm += sv[j] * sv[j];
    const float sc = norm / ((1.0f + norm) * sqrtf(norm + 1e-8f));

    float4 q0, q1, q2, q3;                // one full capsule vector
    q0.x = sv[0]  * sc; q0.y = sv[1]  * sc; q0.z = sv[2]  * sc; q0.w = sv[3]  * sc;
    q1.x = sv[4]  * sc; q1.y = sv[5]  * sc; q1.z = sv[6]  * sc; q1.w = sv[7]  * sc;
    q2.x = sv[8]  * sc; q2.y = sv[9]  * sc; q2.z = sv[10] * sc; q2.w = sv[11] * sc;
    q3.x = sv[12] * sc; q3.y = sv[13] * sc; q3.z = sv[14] * sc; q3.w = sv[15] * sc;

    // out[b] = 2304 float4; this block covers [blk*256, blk*256+256);
    // thread writes 4 consecutive float4 (base % 4 == 0 -> quadrants 0..3).
    float4* ob = reinterpret_cast<float4*>(out + (size_t)b * NR * ND);
    const int base = blk * 256 + lane * 4;
    ob[base + 0] = q0;
    ob[base + 1] = q1;
    ob[base + 2] = q2;
    ob[base + 3] = q3;
}

extern "C" void kernel_launch(void* const* d_in, const int* in_sizes, int n_in,
                              void* d_out, int out_size, void* d_ws, size_t ws_size,
                              hipStream_t stream) {
    const float* x = (const float*)d_in[0];       // [32, 8, 24, 24]
    const float* W = (const float*)d_in[1];       // [32, 576, 8, 16]
    float* out     = (float*)d_out;               // [32, 576, 16]
    float* partial = (float*)d_ws;                // 32*9*16 floats = 18 KB

    void* args[] = { (void*)&x, (void*)&W, (void*)&out, (void*)&partial };
    hipLaunchCooperativeKernel((const void*)caps_coop,
                               dim3(NB * NW), dim3(64), args, 0, stream);
}

// Round 5
// 20.148 us; speedup vs baseline: 2.2057x; 2.2057x over previous
//
#include <hip/hip_runtime.h>

// DigitCapsules: routing collapses analytically (u_hat constant over capsule
// axis -> softmax stays uniform every iteration -> v[b,i,:] =
// squash(mean_r u_core[b,r,:]), identical for all 576 capsules i).
//
// x: [32, 8, 24, 24] fp32, W: [32, 576, 8, 16] fp32, out: [32, 576, 16] fp32.
//
// Single non-cooperative kernel, 288 blocks x 64 threads (full width).
// Lock-free finish: each block publishes a 16-float partial (agent-scope
// stores) + release-stores a MAGIC token; any block observing all 9 tokens
// of its b folds the partials (fixed order -> deterministic), squashes, and
// writes out[b]. >=1 finisher guaranteed; duplicates write identical bytes.
// Finishers reset tokens to 0 so every graph replay starts clean.

#define NB 32
#define NR 576
#define NC 8
#define ND 16
#define NW 9
#define MAGIC 0x51A5C0DEu

__global__ __launch_bounds__(64) void caps_one(const float* __restrict__ x,
                                               const float* __restrict__ W,
                                               float* __restrict__ out,
                                               float* __restrict__ partial,
                                               unsigned* __restrict__ tokens) {
    const int g    = blockIdx.x;          // 0..287
    const int lane = threadIdx.x;         // 0..63  (block == 1 wave)
    const int b    = g / NW;
    const int blk  = g - b * NW;          // 0..8
    const int r    = blk * 64 + lane;     // 9*64 = 576

    // ---------- phase 1: wave partial of sum_r u_core[b,r,:] ----------
    const float* xb = x + (size_t)b * NC * NR;
    const float* Wr = W + ((size_t)b * NR + r) * NC * ND;

    float xv[NC];
#pragma unroll
    for (int k = 0; k < NC; ++k) xv[k] = xb[k * NR + r];   // x2[b,r,k]=x[b,k,r]

    float acc[ND];
#pragma unroll
    for (int j = 0; j < ND; ++j) acc[j] = 0.f;

#pragma unroll
    for (int k = 0; k < NC; ++k) {        // 512 B/lane contiguous W reads
        const float4 w0 = *reinterpret_cast<const float4*>(Wr + k * ND + 0);
        const float4 w1 = *reinterpret_cast<const float4*>(Wr + k * ND + 4);
        const float4 w2 = *reinterpret_cast<const float4*>(Wr + k * ND + 8);
        const float4 w3 = *reinterpret_cast<const float4*>(Wr + k * ND + 12);
        const float xk = xv[k];
        acc[0]  += xk * w0.x;  acc[1]  += xk * w0.y;
        acc[2]  += xk * w0.z;  acc[3]  += xk * w0.w;
        acc[4]  += xk * w1.x;  acc[5]  += xk * w1.y;
        acc[6]  += xk * w1.z;  acc[7]  += xk * w1.w;
        acc[8]  += xk * w2.x;  acc[9]  += xk * w2.y;
        acc[10] += xk * w2.z;  acc[11] += xk * w2.w;
        acc[12] += xk * w3.x;  acc[13] += xk * w3.y;
        acc[14] += xk * w3.z;  acc[15] += xk * w3.w;
    }

#pragma unroll
    for (int j = 0; j < ND; ++j) {        // 64-lane butterfly reduce
#pragma unroll
        for (int m = 1; m < 64; m <<= 1)
            acc[j] += __shfl_xor(acc[j], m, 64);
    }

    // ---------- publish partial + token (lane 0: single-thread release) ----
    if (lane == 0) {
        float* p = partial + ((size_t)b * NW + blk) * ND;
#pragma unroll
        for (int j = 0; j < ND; ++j)
            __hip_atomic_store(p + j, acc[j], __ATOMIC_RELAXED,
                               __HIP_MEMORY_SCOPE_AGENT);
        __hip_atomic_store(&tokens[b * NW + blk], MAGIC, __ATOMIC_RELEASE,
                           __HIP_MEMORY_SCOPE_AGENT);
    }

    // ---------- am I (a) last? lanes 0..8 read this b's 9 tokens ----------
    unsigned tv = MAGIC;
    if (lane < NW)
        tv = __hip_atomic_load(&tokens[b * NW + lane], __ATOMIC_ACQUIRE,
                               __HIP_MEMORY_SCOPE_AGENT);
    if (!__all(tv == MAGIC)) return;      // someone later will finish b

    __threadfence();                      // agent-scope acquire for all lanes

    // ---------- phase 2: fold partials, squash, write out[b] ----------
    __shared__ float sv[ND];
    if (lane < ND) {
        float sj = 0.f;
#pragma unroll
        for (int q = 0; q < NW; ++q)      // fixed order -> deterministic
            sj += __hip_atomic_load(&partial[((size_t)b * NW + q) * ND + lane],
                                    __ATOMIC_RELAXED, __HIP_MEMORY_SCOPE_AGENT);
        sv[lane] = sj * (1.0f / 576.0f);  // uniform softmax coefficient
    }
    __syncthreads();

    float norm = 0.f;
#pragma unroll
    for (int j = 0; j < ND; ++j) norm += sv[j] * sv[j];
    const float sc = norm / ((1.0f + norm) * sqrtf(norm + 1e-8f));

    // out[b] = 2304 float4; idx = s*64 + lane -> quadrant (idx&3) == lane&3
    const int qi = lane & 3;
    float4 vq;
    vq.x = sv[qi * 4 + 0] * sc;
    vq.y = sv[qi * 4 + 1] * sc;
    vq.z = sv[qi * 4 + 2] * sc;
    vq.w = sv[qi * 4 + 3] * sc;

    float4* ob = reinterpret_cast<float4*>(out + (size_t)b * NR * ND);
#pragma unroll
    for (int s = 0; s < 36; ++s) ob[s * 64 + lane] = vq;

    // ---------- reset tokens so the next replay starts clean ----------
    if (lane < NW)
        __hip_atomic_store(&tokens[b * NW + lane], 0u, __ATOMIC_RELAXED,
                           __HIP_MEMORY_SCOPE_AGENT);
}

extern "C" void kernel_launch(void* const* d_in, const int* in_sizes, int n_in,
                              void* d_out, int out_size, void* d_ws, size_t ws_size,
                              hipStream_t stream) {
    const float* x = (const float*)d_in[0];       // [32, 8, 24, 24]
    const float* W = (const float*)d_in[1];       // [32, 576, 8, 16]
    float* out     = (float*)d_out;               // [32, 576, 16]

    float*    partial = (float*)d_ws;                       // 32*9*16 f32 = 18432 B
    unsigned* tokens  = (unsigned*)((char*)d_ws + 18432);   // 32*9 u32  = 1152 B

    caps_one<<<NB * NW, 64, 0, stream>>>(x, W, out, partial, tokens);
}

// Round 6
// 11.804 us; speedup vs baseline: 3.7650x; 1.7070x over previous
//
#include <hip/hip_runtime.h>

// DigitCapsules: routing collapses analytically (u_hat constant over capsule
// axis -> softmax stays uniform on every iteration -> v[b,i,:] =
// squash(mean_r u_core[b,r,:]), identical for all 576 capsules i).
//
// x: [32, 8, 24, 24] fp32, W: [32, 576, 8, 16] fp32, out: [32, 576, 16] fp32.
//
// Final structure (best measured: 11.74-11.80 us): two kernels, both spread
// over ~all CUs. Single-node variants all regressed (fused-narrow 16.4,
// cooperative 44.4, lock-free 20.1): graph-replay overhead ~10 us dominates
// and a node boundary costs less than any intra-kernel cross-block sync.
//   A: 288 blocks x 64 (one wave per 64 routes) -> partial[32][9][16]
//   B: 288 blocks x 256 -> LDS-staged fold + squash, 1 float4 store/thread

#define NB 32
#define NR 576
#define NC 8
#define ND 16
#define NW 9    // partial blocks per batch element

__global__ __launch_bounds__(64) void caps_partial(const float* __restrict__ x,
                                                   const float* __restrict__ W,
                                                   float* __restrict__ partial) {
    const int b    = blockIdx.x;
    const int blk  = blockIdx.y;
    const int lane = threadIdx.x;            // 0..63
    const int r    = blk * 64 + lane;        // 9*64 = 576

    const float* xb = x + (size_t)b * NC * NR;
    const float* Wr = W + ((size_t)b * NR + r) * NC * ND;

    // x2[b, r, k] = x[b, k, r]  (coalesced across lanes per k)
    float xv[NC];
#pragma unroll
    for (int k = 0; k < NC; ++k) xv[k] = xb[k * NR + r];

    float acc[ND];
#pragma unroll
    for (int j = 0; j < ND; ++j) acc[j] = 0.f;

    // u_core[b,r,j] = sum_k x2[b,r,k] * W[b,r,k,j]; 512 B/lane contiguous
#pragma unroll
    for (int k = 0; k < NC; ++k) {
        const float4 w0 = *reinterpret_cast<const float4*>(Wr + k * ND + 0);
        const float4 w1 = *reinterpret_cast<const float4*>(Wr + k * ND + 4);
        const float4 w2 = *reinterpret_cast<const float4*>(Wr + k * ND + 8);
        const float4 w3 = *reinterpret_cast<const float4*>(Wr + k * ND + 12);
        const float xk = xv[k];
        acc[0]  += xk * w0.x;  acc[1]  += xk * w0.y;
        acc[2]  += xk * w0.z;  acc[3]  += xk * w0.w;
        acc[4]  += xk * w1.x;  acc[5]  += xk * w1.y;
        acc[6]  += xk * w1.z;  acc[7]  += xk * w1.w;
        acc[8]  += xk * w2.x;  acc[9]  += xk * w2.y;
        acc[10] += xk * w2.z;  acc[11] += xk * w2.w;
        acc[12] += xk * w3.x;  acc[13] += xk * w3.y;
        acc[14] += xk * w3.z;  acc[15] += xk * w3.w;
    }

    // butterfly reduce each component across the 64-lane wave
#pragma unroll
    for (int j = 0; j < ND; ++j) {
#pragma unroll
        for (int m = 1; m < 64; m <<= 1)
            acc[j] += __shfl_xor(acc[j], m, 64);
    }

    if (lane == 0) {
        float* p = partial + ((size_t)b * NW + blk) * ND;
#pragma unroll
        for (int j = 0; j < ND; ++j) p[j] = acc[j];
    }
}

__global__ __launch_bounds__(256) void caps_finish(const float* __restrict__ partial,
                                                   float* __restrict__ out) {
    const int g     = blockIdx.x;            // 0..287
    const int b     = g / NW;
    const int chunk = g - b * NW;            // 0..8
    const int tid   = threadIdx.x;

    __shared__ float sv[ND];

    // threads 0..15: fold the 9 partials for component j=tid, apply 1/576
    if (tid < ND) {
        const float* p = partial + (size_t)b * NW * ND + tid;
        float sj = 0.f;
#pragma unroll
        for (int q = 0; q < NW; ++q) sj += p[q * ND];
        sv[tid] = sj * (1.0f / 576.0f);
    }
    __syncthreads();

    // every thread: norm + squash scale (broadcast LDS reads)
    float norm = 0.f;
#pragma unroll
    for (int j = 0; j < ND; ++j) norm += sv[j] * sv[j];
    const float sc = norm / ((1.0f + norm) * sqrtf(norm + 1e-8f));

    // out[b] is 2304 float4; this block writes float4 idx chunk*256 + tid.
    const int idx = chunk * 256 + tid;
    const int qi  = idx & 3;
    float4 vq;
    vq.x = sv[qi * 4 + 0] * sc;
    vq.y = sv[qi * 4 + 1] * sc;
    vq.z = sv[qi * 4 + 2] * sc;
    vq.w = sv[qi * 4 + 3] * sc;

    float4* ob = reinterpret_cast<float4*>(out + (size_t)b * NR * ND);
    ob[idx] = vq;
}

extern "C" void kernel_launch(void* const* d_in, const int* in_sizes, int n_in,
                              void* d_out, int out_size, void* d_ws, size_t ws_size,
                              hipStream_t stream) {
    const float* x = (const float*)d_in[0];       // [32, 8, 24, 24]
    const float* W = (const float*)d_in[1];       // [32, 576, 8, 16]
    float* out     = (float*)d_out;               // [32, 576, 16]
    float* partial = (float*)d_ws;                // 32*9*16 floats = 18 KB

    dim3 gridA(NB, NW);
    caps_partial<<<gridA, 64, 0, stream>>>(x, W, partial);
    caps_finish<<<NB * NW, 256, 0, stream>>>(partial, out);
}